// Round 1
// baseline (3331.011 us; speedup 1.0000x reference)
//
#include <hip/hip_runtime.h>

// Problem constants (fixed by the reference)
constexpr int BB = 32;     // batch
constexpr int DD = 384;    // latent dim
constexpr int TN = 4096;   // sequence length
constexpr int KK = 256;    // codebook size
constexpr float BETA = 0.25f;

constexpr int TT  = 64;           // tokens per block
constexpr int DG  = DD / 4;       // 96 float4 groups along D
constexpr int ECH = 4;            // dg-groups per LDS chunk
constexpr int NCH = DG / ECH;     // 24 chunks (even -> clean 2x unroll)

constexpr size_t QSIZE = (size_t)BB * DD * TN;   // 50331648
constexpr size_t ISIZE = (size_t)BB * TN;        // 131072

// --- tiny pre-pass: per-code squared norms into workspace ---
__global__ void e2_kernel(const float* __restrict__ cb, float* __restrict__ e2) {
    int c = threadIdx.x;             // 256 threads == KK
    const float4* row = (const float4*)(cb + (size_t)c * DD);
    float s = 0.f;
    #pragma unroll
    for (int g = 0; g < DG; ++g) {
        float4 v = row[g];
        s += v.x * v.x + v.y * v.y + v.z * v.z + v.w * v.w;
    }
    e2[c] = s;
}

// Async global->LDS DMA, 16B per lane. LDS dest is wave-uniform base +
// lane*16 (hardware semantics); global src is per-lane.
__device__ __forceinline__ void gl_lds16(const void* g, void* l) {
    __builtin_amdgcn_global_load_lds(
        (const __attribute__((address_space(1))) void*)g,
        (__attribute__((address_space(3))) void*)l, 16, 0, 0);
}

// Stage one 4x256-float4 codebook chunk into an LDS buffer, asynchronously.
// Wave wv covers codes [wv*64, wv*64+64): dest base is wave-uniform,
// lane l writes es[dgl][wv*64 + l] <- cb4[(wv*64+l)*DG + dgb + dgl].
__device__ __forceinline__ void stage_es(float4 (&es)[ECH][KK],
                                         const float4* __restrict__ cb4,
                                         int tid, int wv, int dgb) {
    #pragma unroll
    for (int dgl = 0; dgl < ECH; ++dgl)
        gl_lds16(&cb4[(size_t)tid * DG + dgb + dgl], &es[dgl][wv * 64]);
}

// Proven 8 tokens x 8 codes register tile: per dgl-step, 8 broadcast b128
// (tokens) + 8 contiguous b128 (codes) feed 256 v_fmac_f32. Zero bank
// conflicts (do NOT pad es).
__device__ __forceinline__ void compute_chunk(const float4 (&es)[ECH][KK],
                                              const float4 (&xs)[ECH][TT],
                                              float (&acc)[8][8],
                                              int tx, int ty) {
    #pragma unroll
    for (int dgl = 0; dgl < ECH; ++dgl) {
        float4 xv[8];
        #pragma unroll
        for (int i = 0; i < 8; ++i) xv[i] = xs[dgl][ty * 8 + i];   // broadcast
        #pragma unroll
        for (int j = 0; j < 8; ++j) {
            float4 ev = es[dgl][tx + 32 * j];                      // contiguous b128
            #pragma unroll
            for (int i = 0; i < 8; ++i) {
                acc[i][j] += xv[i].x * ev.x;
                acc[i][j] += xv[i].y * ev.y;
                acc[i][j] += xv[i].z * ev.z;
                acc[i][j] += xv[i].w * ev.w;
            }
        }
    }
}

// --- main fused kernel: distances + argmin + quantize + indices + loss ---
// R3: double-buffered LDS + async staging. Codebook chunk goes HBM/L2->LDS
// via global_load_lds (no VGPR round trip); z chunk uses issue-early /
// write-late reg split (only 4 floats live across compute). One barrier per
// chunk; the barrier's vmcnt(0) drain lands AFTER the ~2048-cycle FMA block,
// so staging latency is hidden instead of sitting between two barriers.
// Chunk loop is hand-unrolled x2 so buffer indices are compile-time
// constants (clean alias disambiguation of DMA-writes vs ds_reads).
__global__ __launch_bounds__(256, 2)
void vq_kernel(const float* __restrict__ z, const float* __restrict__ cb,
               const float* __restrict__ e2g, float* __restrict__ out) {
    __shared__ float4 es4[2][ECH][KK];   // 32 KB codebook chunks, [buf][dgl][code]
    __shared__ float4 xs4[2][ECH][TT];   //  8 KB z chunks, [buf][dgl][token]
    __shared__ float  e2s[KK];           //  1 KB
    __shared__ int    idxs[TT];
    __shared__ float  wsum[4];

    const int tid = threadIdx.x;
    const int bid = blockIdx.x;
    const int b   = bid >> 6;                 // TN/TT = 64 tiles per batch
    const int t0  = (bid & 63) * TT;

    const int tx = tid & 31;                  // -> codes  c = tx + 32*j
    const int ty = tid >> 5;                  // -> tokens t = ty*8 + i
    const int wv = tid >> 6;                  // wave id == z dgl row
    const int lt = tid & 63;                  // lane in wave == token (coalesced)

    e2s[tid] = e2g[tid];

    const float*  zb  = z + (size_t)b * DD * TN + t0;
    const float4* cb4 = (const float4*)cb;

    float acc[8][8];
    #pragma unroll
    for (int i = 0; i < 8; ++i)
        #pragma unroll
        for (int j = 0; j < 8; ++j) acc[i][j] = 0.f;

    // prologue: stage chunk 0 into buf0 (latency exposed once, not 24x)
    stage_es(es4[0], cb4, tid, wv, 0);
    {
        float x0 = zb[(size_t)(4 * wv + 0) * TN + lt];
        float x1 = zb[(size_t)(4 * wv + 1) * TN + lt];
        float x2 = zb[(size_t)(4 * wv + 2) * TN + lt];
        float x3 = zb[(size_t)(4 * wv + 3) * TN + lt];
        xs4[0][wv][lt] = make_float4(x0, x1, x2, x3);
    }
    __syncthreads();   // drains vmcnt: all waves' DMA + writes visible

    #pragma unroll 1
    for (int ch = 0; ch < NCH; ch += 2) {
        // ---- even chunk: compute buf0, async-stage chunk ch+1 -> buf1 ----
        {
            const int dgb = (ch + 1) * ECH;           // ch <= 22 so always valid
            stage_es(es4[1], cb4, tid, wv, dgb);      // async DMA, overlaps compute
            float x0 = zb[(size_t)(4 * (dgb + wv) + 0) * TN + lt];  // issue early
            float x1 = zb[(size_t)(4 * (dgb + wv) + 1) * TN + lt];
            float x2 = zb[(size_t)(4 * (dgb + wv) + 2) * TN + lt];
            float x3 = zb[(size_t)(4 * (dgb + wv) + 3) * TN + lt];
            compute_chunk(es4[0], xs4[0], acc, tx, ty);
            xs4[1][wv][lt] = make_float4(x0, x1, x2, x3);           // write late
        }
        __syncthreads();
        // ---- odd chunk: compute buf1, async-stage chunk ch+2 -> buf0 ----
        {
            const bool more = (ch + 2) < NCH;
            const int dgb = (ch + 2) * ECH;
            float x0 = 0.f, x1 = 0.f, x2 = 0.f, x3 = 0.f;
            if (more) {
                stage_es(es4[0], cb4, tid, wv, dgb);
                x0 = zb[(size_t)(4 * (dgb + wv) + 0) * TN + lt];
                x1 = zb[(size_t)(4 * (dgb + wv) + 1) * TN + lt];
                x2 = zb[(size_t)(4 * (dgb + wv) + 2) * TN + lt];
                x3 = zb[(size_t)(4 * (dgb + wv) + 3) * TN + lt];
            }
            compute_chunk(es4[1], xs4[1], acc, tx, ty);
            if (more) xs4[0][wv][lt] = make_float4(x0, x1, x2, x3);
        }
        __syncthreads();
    }

    // per-thread argmin over its 8 codes (c ascending => first-min kept)
    float bv[8]; int bi[8];
    #pragma unroll
    for (int i = 0; i < 8; ++i) { bv[i] = 3.4e38f; bi[i] = 0x7fffffff; }
    #pragma unroll
    for (int j = 0; j < 8; ++j) {
        const int c = tx + 32 * j;
        const float e2c = e2s[c];
        #pragma unroll
        for (int i = 0; i < 8; ++i) {
            float v = e2c - 2.f * acc[i][j];    // x^2 constant per token: drop it
            if (v < bv[i]) { bv[i] = v; bi[i] = c; }
        }
    }
    // cross-lane reduce over the 32 tx lanes (lexicographic: val, then index)
    #pragma unroll
    for (int m = 16; m >= 1; m >>= 1) {
        #pragma unroll
        for (int i = 0; i < 8; ++i) {
            float ov = __shfl_xor(bv[i], m, 64);
            int   oi = __shfl_xor(bi[i], m, 64);
            if (ov < bv[i] || (ov == bv[i] && oi < bi[i])) { bv[i] = ov; bi[i] = oi; }
        }
    }
    if (tx == 0) {
        #pragma unroll
        for (int i = 0; i < 8; ++i) idxs[ty * 8 + i] = bi[i];
    }
    __syncthreads();

    // epilogue: quantize output (coalesced over t), loss partials
    {
        const int myi = idxs[lt];
        const float4* crow = cb4 + (size_t)myi * DG;
        float* outq = out + (size_t)b * DD * TN + t0;
        float lsum = 0.f;
        #pragma unroll
        for (int m = 0; m < 24; ++m) {
            int dg = wv + 4 * m;
            float4 q = crow[dg];                               // L2-hot gather
            float x0 = zb[(size_t)(4 * dg + 0) * TN + lt];     // L2/L3-hot re-read
            float x1 = zb[(size_t)(4 * dg + 1) * TN + lt];
            float x2 = zb[(size_t)(4 * dg + 2) * TN + lt];
            float x3 = zb[(size_t)(4 * dg + 3) * TN + lt];
            float d0 = q.x - x0, d1 = q.y - x1, d2 = q.z - x2, d3 = q.w - x3;
            lsum += d0 * d0 + d1 * d1 + d2 * d2 + d3 * d3;
            outq[(size_t)(4 * dg + 0) * TN + lt] = q.x;
            outq[(size_t)(4 * dg + 1) * TN + lt] = q.y;
            outq[(size_t)(4 * dg + 2) * TN + lt] = q.z;
            outq[(size_t)(4 * dg + 3) * TN + lt] = q.w;
        }
        // indices output (as float: whole out buffer is fp32)
        if (tid < TT)
            out[QSIZE + (size_t)b * TN + t0 + tid] = (float)idxs[tid];

        // loss: wave reduce -> block reduce -> one atomic
        #pragma unroll
        for (int m = 32; m >= 1; m >>= 1) lsum += __shfl_xor(lsum, m, 64);
        if ((tid & 63) == 0) wsum[tid >> 6] = lsum;
        __syncthreads();
        if (tid == 0) {
            float s = wsum[0] + wsum[1] + wsum[2] + wsum[3];
            atomicAdd(out + QSIZE + ISIZE,
                      s * (BETA / (float)((size_t)BB * DD * TN)));
        }
    }
}

extern "C" void kernel_launch(void* const* d_in, const int* in_sizes, int n_in,
                              void* d_out, int out_size, void* d_ws, size_t ws_size,
                              hipStream_t stream) {
    (void)in_sizes; (void)n_in; (void)out_size; (void)ws_size;
    const float* z  = (const float*)d_in[0];
    const float* cb = (const float*)d_in[1];
    float* out  = (float*)d_out;
    float* e2ws = (float*)d_ws;

    // d_out is poisoned 0xAA before every timed launch: zero the loss slot
    hipMemsetAsync(out + QSIZE + ISIZE, 0, sizeof(float), stream);
    e2_kernel<<<dim3(1), dim3(256), 0, stream>>>(cb, e2ws);
    vq_kernel<<<dim3(BB * (TN / TT)), dim3(256), 0, stream>>>(z, cb, e2ws, out);
}

// Round 2
// 1864.354 us; speedup vs baseline: 1.7867x; 1.7867x over previous
//
#include <hip/hip_runtime.h>

// Problem constants (fixed by the reference)
constexpr int BB = 32;     // batch
constexpr int DD = 384;    // latent dim
constexpr int TN = 4096;   // sequence length
constexpr int KK = 256;    // codebook size
constexpr float BETA = 0.25f;

constexpr int TT  = 64;           // tokens per block
constexpr int DG  = DD / 4;       // 96 float4 groups along D
constexpr int ECH = 4;            // dg-groups per LDS chunk
constexpr int NCH = DG / ECH;     // 24 chunks

constexpr size_t QSIZE = (size_t)BB * DD * TN;   // 50331648
constexpr size_t ISIZE = (size_t)BB * TN;        // 131072

// --- tiny pre-pass: per-code squared norms into workspace ---
__global__ void e2_kernel(const float* __restrict__ cb, float* __restrict__ e2) {
    int c = threadIdx.x;             // 256 threads == KK
    const float4* row = (const float4*)(cb + (size_t)c * DD);
    float s = 0.f;
    #pragma unroll
    for (int g = 0; g < DG; ++g) {
        float4 v = row[g];
        s += v.x * v.x + v.y * v.y + v.z * v.z + v.w * v.w;
    }
    e2[c] = s;
}

// --- main fused kernel: distances + argmin + quantize + indices + loss ---
// 8 tokens x 8 codes per thread: per dgl-step a wave does 8 contiguous
// ds_read_b128 (codes) + 8 broadcast b128 (tokens) feeding 256 v_fmac_f32.
// Hard-won structure lessons (previous session R2 + this session R1):
//   * NO padding on es4 (contiguous b128 is conflict-free; padding caused
//     6.3M bank conflicts).
//   * NO staging values held across compute, and NO global_load_lds DMA:
//     both push the 64-reg accumulator into scratch spill (R1: 8.4 GB of
//     scratch writes, 6.6x regression). Staging regs must be transient
//     between the two barriers only.
// R2 change (this session): __launch_bounds__(256, 4) instead of (256, 2).
// The kernel only uses ~104 VGPRs, so the 128-reg cap still cannot spill,
// and 4 blocks/CU (vs 2) lets one block's staging drain + barrier
// convergence hide under another block's 2048-cycle FMA phase (VALUBusy
// was pinned at 50% with the structural stall exposed every chunk).
__global__ __launch_bounds__(256, 4)
void vq_kernel(const float* __restrict__ z, const float* __restrict__ cb,
               const float* __restrict__ e2g, float* __restrict__ out) {
    __shared__ float4 es4[ECH][KK];   // 16 KB codebook chunk, [dgl][code]
    __shared__ float4 xs4[ECH][TT];   //  4 KB z chunk, [dgl][token]
    __shared__ float  e2s[KK];        //  1 KB
    __shared__ int    idxs[TT];
    __shared__ float  wsum[4];

    const int tid = threadIdx.x;
    const int bid = blockIdx.x;
    const int b   = bid >> 6;                 // TN/TT = 64 tiles per batch
    const int t0  = (bid & 63) * TT;

    const int tx = tid & 31;                  // -> codes  c = tx + 32*j
    const int ty = tid >> 5;                  // -> tokens t = ty*8 + i

    e2s[tid] = e2g[tid];

    const float*  zb  = z + (size_t)b * DD * TN + t0;
    const float4* cb4 = (const float4*)cb;

    // staging lane mapping (transient loads each chunk, no cross-barrier regs)
    const int xr  = tid >> 6;      // z: dgl row (0..3)
    const int xtt = tid & 63;      // z: token (coalesced)

    float acc[8][8];
    #pragma unroll
    for (int i = 0; i < 8; ++i)
        #pragma unroll
        for (int j = 0; j < 8; ++j) acc[i][j] = 0.f;

    for (int ch = 0; ch < NCH; ++ch) {
        const int dgb = ch * ECH;
        // issue global loads first (overlap with other blocks' compute)
        float4 ev0 = cb4[(size_t)tid * DG + dgb + 0];   // 64 contiguous B/row
        float4 ev1 = cb4[(size_t)tid * DG + dgb + 1];
        float4 ev2 = cb4[(size_t)tid * DG + dgb + 2];
        float4 ev3 = cb4[(size_t)tid * DG + dgb + 3];
        float x0 = zb[(size_t)(4 * (dgb + xr) + 0) * TN + xtt];  // coalesced
        float x1 = zb[(size_t)(4 * (dgb + xr) + 1) * TN + xtt];
        float x2 = zb[(size_t)(4 * (dgb + xr) + 2) * TN + xtt];
        float x3 = zb[(size_t)(4 * (dgb + xr) + 3) * TN + xtt];
        __syncthreads();                     // prev-iter readers done
        es4[0][tid] = ev0;                   // lane-contiguous b128 writes
        es4[1][tid] = ev1;
        es4[2][tid] = ev2;
        es4[3][tid] = ev3;
        xs4[xr][xtt] = make_float4(x0, x1, x2, x3);
        __syncthreads();

        #pragma unroll
        for (int dgl = 0; dgl < ECH; ++dgl) {
            float4 xv[8];
            #pragma unroll
            for (int i = 0; i < 8; ++i) xv[i] = xs4[dgl][ty * 8 + i];  // broadcast
            #pragma unroll
            for (int j = 0; j < 8; ++j) {
                float4 ev = es4[dgl][tx + 32 * j];                     // contiguous b128
                #pragma unroll
                for (int i = 0; i < 8; ++i) {
                    acc[i][j] += xv[i].x * ev.x;
                    acc[i][j] += xv[i].y * ev.y;
                    acc[i][j] += xv[i].z * ev.z;
                    acc[i][j] += xv[i].w * ev.w;
                }
            }
        }
    }

    // per-thread argmin over its 8 codes (c ascending => first-min kept)
    float bv[8]; int bi[8];
    #pragma unroll
    for (int i = 0; i < 8; ++i) { bv[i] = 3.4e38f; bi[i] = 0x7fffffff; }
    #pragma unroll
    for (int j = 0; j < 8; ++j) {
        const int c = tx + 32 * j;
        const float e2c = e2s[c];
        #pragma unroll
        for (int i = 0; i < 8; ++i) {
            float v = e2c - 2.f * acc[i][j];    // x^2 constant per token: drop it
            if (v < bv[i]) { bv[i] = v; bi[i] = c; }
        }
    }
    // cross-lane reduce over the 32 tx lanes (lexicographic: val, then index)
    #pragma unroll
    for (int m = 16; m >= 1; m >>= 1) {
        #pragma unroll
        for (int i = 0; i < 8; ++i) {
            float ov = __shfl_xor(bv[i], m, 64);
            int   oi = __shfl_xor(bi[i], m, 64);
            if (ov < bv[i] || (ov == bv[i] && oi < bi[i])) { bv[i] = ov; bi[i] = oi; }
        }
    }
    if (tx == 0) {
        #pragma unroll
        for (int i = 0; i < 8; ++i) idxs[ty * 8 + i] = bi[i];
    }
    __syncthreads();

    // epilogue: quantize output (coalesced over t), loss partials
    {
        const int myi = idxs[xtt];
        const float4* crow = cb4 + (size_t)myi * DG;
        float* outq = out + (size_t)b * DD * TN + t0;
        float lsum = 0.f;
        #pragma unroll
        for (int m = 0; m < 24; ++m) {
            int dg = xr + 4 * m;
            float4 q = crow[dg];                               // L2-hot gather
            float x0 = zb[(size_t)(4 * dg + 0) * TN + xtt];    // coalesced re-read
            float x1 = zb[(size_t)(4 * dg + 1) * TN + xtt];
            float x2 = zb[(size_t)(4 * dg + 2) * TN + xtt];
            float x3 = zb[(size_t)(4 * dg + 3) * TN + xtt];
            float d0 = q.x - x0, d1 = q.y - x1, d2 = q.z - x2, d3 = q.w - x3;
            lsum += d0 * d0 + d1 * d1 + d2 * d2 + d3 * d3;
            outq[(size_t)(4 * dg + 0) * TN + xtt] = q.x;
            outq[(size_t)(4 * dg + 1) * TN + xtt] = q.y;
            outq[(size_t)(4 * dg + 2) * TN + xtt] = q.z;
            outq[(size_t)(4 * dg + 3) * TN + xtt] = q.w;
        }
        // indices output (as float: whole out buffer is fp32)
        if (tid < TT)
            out[QSIZE + (size_t)b * TN + t0 + tid] = (float)idxs[tid];

        // loss: wave reduce -> block reduce -> one atomic
        #pragma unroll
        for (int m = 32; m >= 1; m >>= 1) lsum += __shfl_xor(lsum, m, 64);
        if ((tid & 63) == 0) wsum[tid >> 6] = lsum;
        __syncthreads();
        if (tid == 0) {
            float s = wsum[0] + wsum[1] + wsum[2] + wsum[3];
            atomicAdd(out + QSIZE + ISIZE,
                      s * (BETA / (float)((size_t)BB * DD * TN)));
        }
    }
}

extern "C" void kernel_launch(void* const* d_in, const int* in_sizes, int n_in,
                              void* d_out, int out_size, void* d_ws, size_t ws_size,
                              hipStream_t stream) {
    (void)in_sizes; (void)n_in; (void)out_size; (void)ws_size;
    const float* z  = (const float*)d_in[0];
    const float* cb = (const float*)d_in[1];
    float* out  = (float*)d_out;
    float* e2ws = (float*)d_ws;

    // d_out is poisoned 0xAA before every timed launch: zero the loss slot
    hipMemsetAsync(out + QSIZE + ISIZE, 0, sizeof(float), stream);
    e2_kernel<<<dim3(1), dim3(256), 0, stream>>>(cb, e2ws);
    vq_kernel<<<dim3(BB * (TN / TT)), dim3(256), 0, stream>>>(z, cb, e2ws, out);
}

// Round 3
// 647.891 us; speedup vs baseline: 5.1413x; 2.8776x over previous
//
#include <hip/hip_runtime.h>

// Problem constants (fixed by the reference)
constexpr int BB = 32;     // batch
constexpr int DD = 384;    // latent dim
constexpr int TN = 4096;   // sequence length
constexpr int KK = 256;    // codebook size
constexpr float BETA = 0.25f;

constexpr int TT  = 64;           // tokens per block
constexpr int DG  = DD / 4;       // 96 float4 groups along D
constexpr int ECH = 4;            // dg-groups per LDS chunk
constexpr int NCH = DG / ECH;     // 24 chunks

constexpr size_t QSIZE = (size_t)BB * DD * TN;   // 50331648
constexpr size_t ISIZE = (size_t)BB * TN;        // 131072

// --- pre-pass: per-code squared norms. One wave per code (256 blocks):
// the old grid(1) version serialized ~384 KB of cold reads on one CU and
// cost tens of µs of the bench gap. ---
__global__ void e2_kernel(const float* __restrict__ cb, float* __restrict__ e2) {
    const int c = blockIdx.x;                 // 0..255
    const int t = threadIdx.x;                // 0..63
    const float4* row = (const float4*)(cb + (size_t)c * DD);
    float4 v = row[t];                        // groups 0..63
    float s = v.x * v.x + v.y * v.y + v.z * v.z + v.w * v.w;
    if (t < DG - 64) {                        // groups 64..95 (t < 32)
        float4 w = row[t + 64];
        s += w.x * w.x + w.y * w.y + w.z * w.z + w.w * w.w;
    }
    #pragma unroll
    for (int m = 32; m >= 1; m >>= 1) s += __shfl_xor(s, m, 64);
    if (t == 0) e2[c] = s;
}

// --- main fused kernel: distances + argmin + quantize + indices + loss ---
// 8 tokens x 8 codes per thread: per dgl-step a wave does 8 contiguous
// ds_read_b128 (codes) + 8 broadcast b128 (tokens) feeding 256 v_fmac_f32.
// Hard-won structure lessons (prev session R2 + this session R1/R2):
//   * NO padding on es4 (contiguous b128 is conflict-free).
//   * NO global_load_lds DMA and NO bulk (>=20 reg) prefetch held across
//     compute: both spilled the accumulator (R1: 8.4 GB scratch writes).
//   * __launch_bounds__ MUST stay (256,2): (256,4) made the allocator
//     squeeze to 64 VGPRs and spill acc (R2: 4x slowdown). The kernel's
//     ~104 actual VGPRs already permit ~4 blocks/CU at runtime.
// R3 change: prefetch ONLY the 4 z scalars (HBM-cold, ~900 cyc) one chunk
// ahead, issued AFTER the second barrier so the latency retires under the
// ~2048-cycle FMA block even if hipcc drains vmcnt at barriers. The
// codebook chunk load stays transient (L2-hot, ~300 cyc exposure only).
__global__ __launch_bounds__(256, 2)
void vq_kernel(const float* __restrict__ z, const float* __restrict__ cb,
               const float* __restrict__ e2g, float* __restrict__ out) {
    __shared__ float4 es4[ECH][KK];   // 16 KB codebook chunk, [dgl][code]
    __shared__ float4 xs4[ECH][TT];   //  4 KB z chunk, [dgl][token]
    __shared__ float  e2s[KK];        //  1 KB
    __shared__ int    idxs[TT];
    __shared__ float  wsum[4];

    const int tid = threadIdx.x;
    const int bid = blockIdx.x;
    const int b   = bid >> 6;                 // TN/TT = 64 tiles per batch
    const int t0  = (bid & 63) * TT;

    const int tx = tid & 31;                  // -> codes  c = tx + 32*j
    const int ty = tid >> 5;                  // -> tokens t = ty*8 + i

    e2s[tid] = e2g[tid];

    const float*  zb  = z + (size_t)b * DD * TN + t0;
    const float4* cb4 = (const float4*)cb;

    // staging lane mapping
    const int xr  = tid >> 6;      // z: dgl row (0..3)
    const int xtt = tid & 63;      // z: token (coalesced)

    float acc[8][8];
    #pragma unroll
    for (int i = 0; i < 8; ++i)
        #pragma unroll
        for (int j = 0; j < 8; ++j) acc[i][j] = 0.f;

    // prologue: prefetch chunk 0's z rows (latency exposed once, not 24x)
    float xh0 = zb[(size_t)(4 * xr + 0) * TN + xtt];
    float xh1 = zb[(size_t)(4 * xr + 1) * TN + xtt];
    float xh2 = zb[(size_t)(4 * xr + 2) * TN + xtt];
    float xh3 = zb[(size_t)(4 * xr + 3) * TN + xtt];

    for (int ch = 0; ch < NCH; ++ch) {
        const int dgb = ch * ECH;
        // codebook chunk: transient regs, L2-hot after first pass
        float4 ev0 = cb4[(size_t)tid * DG + dgb + 0];   // 64 contiguous B/row
        float4 ev1 = cb4[(size_t)tid * DG + dgb + 1];
        float4 ev2 = cb4[(size_t)tid * DG + dgb + 2];
        float4 ev3 = cb4[(size_t)tid * DG + dgb + 3];
        __syncthreads();                     // prev-iter readers done
        es4[0][tid] = ev0;                   // lane-contiguous b128 writes
        es4[1][tid] = ev1;
        es4[2][tid] = ev2;
        es4[3][tid] = ev3;
        xs4[xr][xtt] = make_float4(xh0, xh1, xh2, xh3);  // already in regs
        __syncthreads();

        // issue next chunk's z loads NOW: ~900-cyc HBM latency retires
        // under the FMA block below, on either side of any barrier drain.
        const bool more = (ch + 1) < NCH;
        float nx0 = 0.f, nx1 = 0.f, nx2 = 0.f, nx3 = 0.f;
        if (more) {
            const int dgn = dgb + ECH;
            nx0 = zb[(size_t)(4 * (dgn + xr) + 0) * TN + xtt];
            nx1 = zb[(size_t)(4 * (dgn + xr) + 1) * TN + xtt];
            nx2 = zb[(size_t)(4 * (dgn + xr) + 2) * TN + xtt];
            nx3 = zb[(size_t)(4 * (dgn + xr) + 3) * TN + xtt];
        }

        #pragma unroll
        for (int dgl = 0; dgl < ECH; ++dgl) {
            float4 xv[8];
            #pragma unroll
            for (int i = 0; i < 8; ++i) xv[i] = xs4[dgl][ty * 8 + i];  // broadcast
            #pragma unroll
            for (int j = 0; j < 8; ++j) {
                float4 ev = es4[dgl][tx + 32 * j];                     // contiguous b128
                #pragma unroll
                for (int i = 0; i < 8; ++i) {
                    acc[i][j] += xv[i].x * ev.x;
                    acc[i][j] += xv[i].y * ev.y;
                    acc[i][j] += xv[i].z * ev.z;
                    acc[i][j] += xv[i].w * ev.w;
                }
            }
        }

        if (more) { xh0 = nx0; xh1 = nx1; xh2 = nx2; xh3 = nx3; }
    }

    // per-thread argmin over its 8 codes (c ascending => first-min kept)
    float bv[8]; int bi[8];
    #pragma unroll
    for (int i = 0; i < 8; ++i) { bv[i] = 3.4e38f; bi[i] = 0x7fffffff; }
    #pragma unroll
    for (int j = 0; j < 8; ++j) {
        const int c = tx + 32 * j;
        const float e2c = e2s[c];
        #pragma unroll
        for (int i = 0; i < 8; ++i) {
            float v = e2c - 2.f * acc[i][j];    // x^2 constant per token: drop it
            if (v < bv[i]) { bv[i] = v; bi[i] = c; }
        }
    }
    // cross-lane reduce over the 32 tx lanes (lexicographic: val, then index)
    #pragma unroll
    for (int m = 16; m >= 1; m >>= 1) {
        #pragma unroll
        for (int i = 0; i < 8; ++i) {
            float ov = __shfl_xor(bv[i], m, 64);
            int   oi = __shfl_xor(bi[i], m, 64);
            if (ov < bv[i] || (ov == bv[i] && oi < bi[i])) { bv[i] = ov; bi[i] = oi; }
        }
    }
    if (tx == 0) {
        #pragma unroll
        for (int i = 0; i < 8; ++i) idxs[ty * 8 + i] = bi[i];
    }
    __syncthreads();

    // epilogue: quantize output (coalesced over t), loss partials
    {
        const int myi = idxs[xtt];
        const float4* crow = cb4 + (size_t)myi * DG;
        float* outq = out + (size_t)b * DD * TN + t0;
        float lsum = 0.f;
        #pragma unroll
        for (int m = 0; m < 24; ++m) {
            int dg = xr + 4 * m;
            float4 q = crow[dg];                               // L2-hot gather
            float x0 = zb[(size_t)(4 * dg + 0) * TN + xtt];    // L3-hot re-read
            float x1 = zb[(size_t)(4 * dg + 1) * TN + xtt];
            float x2 = zb[(size_t)(4 * dg + 2) * TN + xtt];
            float x3 = zb[(size_t)(4 * dg + 3) * TN + xtt];
            float d0 = q.x - x0, d1 = q.y - x1, d2 = q.z - x2, d3 = q.w - x3;
            lsum += d0 * d0 + d1 * d1 + d2 * d2 + d3 * d3;
            outq[(size_t)(4 * dg + 0) * TN + xtt] = q.x;
            outq[(size_t)(4 * dg + 1) * TN + xtt] = q.y;
            outq[(size_t)(4 * dg + 2) * TN + xtt] = q.z;
            outq[(size_t)(4 * dg + 3) * TN + xtt] = q.w;
        }
        // indices output (as float: whole out buffer is fp32)
        if (tid < TT)
            out[QSIZE + (size_t)b * TN + t0 + tid] = (float)idxs[tid];

        // loss: wave reduce -> block reduce -> one atomic
        #pragma unroll
        for (int m = 32; m >= 1; m >>= 1) lsum += __shfl_xor(lsum, m, 64);
        if ((tid & 63) == 0) wsum[tid >> 6] = lsum;
        __syncthreads();
        if (tid == 0) {
            float s = wsum[0] + wsum[1] + wsum[2] + wsum[3];
            atomicAdd(out + QSIZE + ISIZE,
                      s * (BETA / (float)((size_t)BB * DD * TN)));
        }
    }
}

extern "C" void kernel_launch(void* const* d_in, const int* in_sizes, int n_in,
                              void* d_out, int out_size, void* d_ws, size_t ws_size,
                              hipStream_t stream) {
    (void)in_sizes; (void)n_in; (void)out_size; (void)ws_size;
    const float* z  = (const float*)d_in[0];
    const float* cb = (const float*)d_in[1];
    float* out  = (float*)d_out;
    float* e2ws = (float*)d_ws;

    // d_out is poisoned 0xAA before every timed launch: zero the loss slot
    hipMemsetAsync(out + QSIZE + ISIZE, 0, sizeof(float), stream);
    e2_kernel<<<dim3(KK), dim3(64), 0, stream>>>(cb, e2ws);
    vq_kernel<<<dim3(BB * (TN / TT)), dim3(256), 0, stream>>>(z, cb, e2ws, out);
}